// Round 1
// baseline (1736.049 us; speedup 1.0000x reference)
//
#include <hip/hip_runtime.h>
#include <hip/hip_bf16.h>

#define HDIM 128
#define NREL 16
#define NBASES 8
#define TILE 64        // output rows per block (dst-tile)
#define LDSF 132       // fp32 row stride for A tile: 132 mod 32 banks = 4 -> 2-way (free)

typedef short bf16x8 __attribute__((ext_vector_type(8)));
typedef short s16x4 __attribute__((ext_vector_type(4)));
typedef float f32x4 __attribute__((ext_vector_type(4)));

static __device__ __forceinline__ short f2bf(float x) {
    __hip_bfloat16 b = __float2bfloat16(x);
    return *(short*)&b;
}
static __device__ __forceinline__ float bf2f(short u) {
    unsigned v = ((unsigned)(unsigned short)u) << 16;
    return __uint_as_float(v);
}

// ---------------- weight prep (fp32 in -> bf16 out) ----------------
// wt[r][o][i] = W_r[i][o] = sum_b wcomp[r][b] * basis[b][i][o]
__global__ void compute_wt(const float* __restrict__ basis,
                           const float* __restrict__ wcomp,
                           short* __restrict__ wt) {
    int ro = blockIdx.x;
    int r = ro >> 7, o = ro & 127;
    int i = threadIdx.x;
    float acc = 0.f;
#pragma unroll
    for (int b = 0; b < NBASES; ++b)
        acc += wcomp[r * NBASES + b] * basis[(b * HDIM + i) * HDIM + o];
    wt[(size_t)(r * HDIM + o) * HDIM + i] = f2bf(acc);
}

// lwT[o][i] = loop_w[i][o]  (fp32 -> bf16)
__global__ void transpose128(const float* __restrict__ in, short* __restrict__ out) {
    int o = blockIdx.x, i = threadIdx.x;
    out[o * HDIM + i] = f2bf(in[i * HDIM + o]);
}

// fp32 -> bf16 cast (vectorized)
__global__ void cast_bf16(const float* __restrict__ in, short* __restrict__ out, int n4) {
    for (int i = blockIdx.x * blockDim.x + threadIdx.x; i < n4; i += gridDim.x * blockDim.x) {
        f32x4 v = ((const f32x4*)in)[i];
        s16x4 o;
#pragma unroll
        for (int j = 0; j < 4; ++j) o[j] = f2bf(v[j]);
        ((s16x4*)out)[i] = o;
    }
}

__global__ void zero_i32(int* __restrict__ p, int n) {
    int i = blockIdx.x * blockDim.x + threadIdx.x;
    if (i < n) p[i] = 0;
}

// ---------------- bucket sort: (dst-tile, rel) buckets ----------------
// 12512 buckets (782 tiles x 16 rels), ~64 edges each -> global atomics are
// essentially contention-free. Order WITHIN a bucket is irrelevant (LDS
// accumulation in the layer kernel is order-insensitive up to fp32 rounding).
__global__ __launch_bounds__(256) void hist_b(const int* __restrict__ dst,
                                              const int* __restrict__ rel, int n,
                                              int* __restrict__ cnt) {
    for (int i = blockIdx.x * blockDim.x + threadIdx.x; i < n; i += gridDim.x * blockDim.x) {
        int b = (dst[i] >> 6) * NREL + rel[i];
        atomicAdd(&cnt[b], 1);
    }
}

__global__ __launch_bounds__(1024) void scan_b(const int* __restrict__ cnt, int nb,
                                               int* __restrict__ off, int* __restrict__ cur) {
    __shared__ int part[1024];
    int t = threadIdx.x;
    int per = (nb + 1023) >> 10;
    int lo = t * per, hi = min(nb, lo + per);
    int s = 0;
    for (int i = lo; i < hi; ++i) s += cnt[i];
    part[t] = s;
    __syncthreads();
    for (int d = 1; d < 1024; d <<= 1) {
        int v = part[t];
        int u = (t >= d) ? part[t - d] : 0;
        __syncthreads();
        part[t] = v + u;
        __syncthreads();
    }
    int run = (t > 0) ? part[t - 1] : 0;
    for (int i = lo; i < hi; ++i) {
        off[i] = run; cur[i] = run;
        run += cnt[i];
    }
    if (t == 0) off[nb] = part[1023];
}

// pack: src (16 bits, n_ent=50000 < 65536) | (dst & 63) << 16
__global__ __launch_bounds__(256) void scatter_b(const int* __restrict__ src,
                                                 const int* __restrict__ dst,
                                                 const int* __restrict__ rel, int n,
                                                 int* __restrict__ cur,
                                                 int* __restrict__ edge_s) {
    for (int i = blockIdx.x * blockDim.x + threadIdx.x; i < n; i += gridDim.x * blockDim.x) {
        int d = dst[i];
        int b = (d >> 6) * NREL + rel[i];
        int p = atomicAdd(&cur[b], 1);
        edge_s[p] = (src[i] & 0xFFFF) | ((d & 63) << 16);
    }
}

// ---------------- fused RGCN layer ----------------
// Block = 64 output rows, 256 threads (4 waves, each wave = 64 rows x 32 cols).
// For r in [0,16): scatter-accumulate h[src] of bucket (tile,r) into fp32 LDS
// tile A (LDS atomics, zero global atomics), then acc += A @ W_r via MFMA.
// r==16 is the self-loop: A = h[tile rows], B = loop_w^T.
// Epilogue: out = relu(acc + bias), written ONCE (bf16 for layer1, f32 for layer2).
__global__ __launch_bounds__(256, 3) void rgcn_layer(
    const short* __restrict__ h,      // bf16 [N][128]
    const short* __restrict__ wt,     // bf16 [16][o][i]
    const short* __restrict__ lwT,    // bf16 [o][i] = loop_w[i][o]
    const float* __restrict__ bias,   // fp32 [128]
    const int* __restrict__ off,      // [ntiles*16 + 1]
    const int* __restrict__ edge_s,   // packed src | dloc<<16, bucket-sorted
    short* __restrict__ out_bf,       // layer-1 output (bf16) or nullptr
    float* __restrict__ out_f,        // layer-2 output (fp32) or nullptr
    int N) {
    __shared__ __align__(16) float A[TILE * LDSF];
    int tile = blockIdx.x;
    int n0 = tile * TILE;
    int tid = threadIdx.x;
    int wave = tid >> 6, lane = tid & 63;
    int nq = wave * 32;               // wave owns cols [nq, nq+32)
    int lr = lane & 15, quad = lane >> 4;
    int g16 = tid >> 4, lane16 = tid & 15;   // 16 groups x 16 lanes for gather

    f32x4 acc[4][2] = {};             // m: 4x16 rows, n: 2x16 cols per wave

    for (int r = 0; r <= NREL; ++r) {
        // B fragments for this relation (L2-hot; 32KB per r per block, no dup)
        const short* br = (r < NREL) ? (wt + (size_t)r * HDIM * HDIM) : lwT;
        bf16x8 b[4][2];
#pragma unroll
        for (int kk = 0; kk < 4; ++kk)
#pragma unroll
            for (int ni = 0; ni < 2; ++ni)
                b[kk][ni] = *(const bf16x8*)(br + (nq + ni * 16 + lr) * HDIM + kk * 32 + quad * 8);

        // zero the accumulation tile
        for (int i = tid; i < TILE * LDSF / 4; i += 256)
            ((f32x4*)A)[i] = (f32x4){0.f, 0.f, 0.f, 0.f};
        __syncthreads();

        // build A
        if (r < NREL) {
            int e0 = off[tile * NREL + r], e1 = off[tile * NREL + r + 1];
            for (int e = e0 + g16; e < e1; e += 16) {
                int pk = edge_s[e];
                int s = pk & 0xFFFF;
                int dl = (pk >> 16) & 63;
                bf16x8 v = *(const bf16x8*)(h + (size_t)s * HDIM + lane16 * 8);
                float* arow = A + dl * LDSF + lane16 * 8;
#pragma unroll
                for (int c = 0; c < 8; ++c) atomicAdd(arow + c, bf2f(v[c]));
            }
        } else {
            // self-loop: direct fill (no atomics); rows >= N stay zero
            for (int row = g16; row < TILE; row += 16) {
                int g = n0 + row;
                if (g < N) {
                    bf16x8 v = *(const bf16x8*)(h + (size_t)g * HDIM + lane16 * 8);
                    float* arow = A + row * LDSF + lane16 * 8;
#pragma unroll
                    for (int c = 0; c < 8; ++c) arow[c] = bf2f(v[c]);
                }
            }
        }
        __syncthreads();

        // MFMA: acc += bf16(A) @ B_r
#pragma unroll
        for (int kk = 0; kk < 4; ++kk) {
            int kb = kk * 32 + quad * 8;
            bf16x8 a[4];
#pragma unroll
            for (int mi = 0; mi < 4; ++mi) {
                const float* ap = A + (mi * 16 + lr) * LDSF + kb;
                f32x4 vlo = *(const f32x4*)ap;
                f32x4 vhi = *(const f32x4*)(ap + 4);
                bf16x8 av;
#pragma unroll
                for (int c = 0; c < 4; ++c) { av[c] = f2bf(vlo[c]); av[c + 4] = f2bf(vhi[c]); }
                a[mi] = av;
            }
#pragma unroll
            for (int mi = 0; mi < 4; ++mi)
#pragma unroll
                for (int ni = 0; ni < 2; ++ni)
                    acc[mi][ni] = __builtin_amdgcn_mfma_f32_16x16x32_bf16(a[mi], b[kk][ni], acc[mi][ni], 0, 0, 0);
        }
        __syncthreads();   // A free for next r's zero
    }

    // epilogue: bias + relu, single non-atomic store
    // C/D: col = lane&15 (n), row = quad*4 + reg (m)  [m89]
#pragma unroll
    for (int mi = 0; mi < 4; ++mi) {
#pragma unroll
        for (int reg = 0; reg < 4; ++reg) {
            int g = n0 + mi * 16 + quad * 4 + reg;
            if (g < N) {
#pragma unroll
                for (int ni = 0; ni < 2; ++ni) {
                    int n = nq + ni * 16 + lr;
                    float v = acc[mi][ni][reg] + bias[n];
                    v = v > 0.f ? v : 0.f;
                    if (out_bf) out_bf[(size_t)g * HDIM + n] = f2bf(v);
                    else        out_f[(size_t)g * HDIM + n] = v;
                }
            }
        }
    }
}

extern "C" void kernel_launch(void* const* d_in, const int* in_sizes, int n_in,
                              void* d_out, int out_size, void* d_ws, size_t ws_size,
                              hipStream_t stream) {
    const float* emb    = (const float*)d_in[0];
    const float* basis1 = (const float*)d_in[1];
    const float* wc1    = (const float*)d_in[2];
    const float* lw1    = (const float*)d_in[3];
    const float* bias1  = (const float*)d_in[4];
    const float* basis2 = (const float*)d_in[5];
    const float* wc2    = (const float*)d_in[6];
    const float* lw2    = (const float*)d_in[7];
    const float* bias2  = (const float*)d_in[8];
    const int* src = (const int*)d_in[9];
    const int* dst = (const int*)d_in[10];
    const int* rel = (const int*)d_in[11];

    int n_ent = in_sizes[0] / HDIM;
    int n_edges = in_sizes[9];
    int ntiles = (n_ent + TILE - 1) / TILE;
    int nbuckets = ntiles * NREL;

    char* ws = (char*)d_ws;
    size_t wo = 0;
    auto alloc = [&](size_t bytes) {
        void* p = ws + wo;
        wo = (wo + bytes + 255) & ~(size_t)255;
        return p;
    };
    int* cnt    = (int*)alloc((size_t)nbuckets * 4);
    int* off    = (int*)alloc((size_t)(nbuckets + 1) * 4);
    int* curp   = (int*)alloc((size_t)nbuckets * 4);
    short* wt1  = (short*)alloc((size_t)NREL * HDIM * HDIM * 2);
    short* wt2  = (short*)alloc((size_t)NREL * HDIM * HDIM * 2);
    short* lw1T = (short*)alloc((size_t)HDIM * HDIM * 2);
    short* lw2T = (short*)alloc((size_t)HDIM * HDIM * 2);
    short* h0   = (short*)alloc((size_t)n_ent * HDIM * 2);
    short* h1   = (short*)alloc((size_t)n_ent * HDIM * 2);
    int* edge_s = (int*)alloc((size_t)n_edges * 4);

    // weight prep + input cast (independent small kernels)
    compute_wt<<<NREL * HDIM, HDIM, 0, stream>>>(basis1, wc1, wt1);
    compute_wt<<<NREL * HDIM, HDIM, 0, stream>>>(basis2, wc2, wt2);
    transpose128<<<HDIM, HDIM, 0, stream>>>(lw1, lw1T);
    transpose128<<<HDIM, HDIM, 0, stream>>>(lw2, lw2T);
    cast_bf16<<<512, 256, 0, stream>>>(emb, h0, n_ent * HDIM / 4);

    // bucket sort (once; reused by both layers)
    zero_i32<<<(nbuckets + 255) / 256, 256, 0, stream>>>(cnt, nbuckets);
    hist_b<<<1024, 256, 0, stream>>>(dst, rel, n_edges, cnt);
    scan_b<<<1, 1024, 0, stream>>>(cnt, nbuckets, off, curp);
    scatter_b<<<1024, 256, 0, stream>>>(src, dst, rel, n_edges, curp, edge_s);

    // fused layers: zero global atomics, single store per output element
    rgcn_layer<<<ntiles, 256, 0, stream>>>(h0, wt1, lw1T, bias1, off, edge_s,
                                           h1, nullptr, n_ent);
    rgcn_layer<<<ntiles, 256, 0, stream>>>(h1, wt2, lw2T, bias2, off, edge_s,
                                           nullptr, (float*)d_out, n_ent);
}